// Round 14
// baseline (287.538 us; speedup 1.0000x reference)
//
#include <hip/hip_runtime.h>
#include <hip/hip_bf16.h>
#include <cstdint>

#define D_MODEL 1024
#define N_HEADS 16
#define SEQ     2048
#define BATCH   4
#define M_TOT   (BATCH*SEQ)   // 8192

typedef short bf16x8 __attribute__((ext_vector_type(8)));
typedef short bf16x4 __attribute__((ext_vector_type(4)));
typedef float f32x4  __attribute__((ext_vector_type(4)));
typedef __hip_bfloat16 bf16;

// async global->LDS, 16B/lane; dest = wave-uniform base + lane*16 (m97/m104)
__device__ __forceinline__ void gld_lds16(const void* g, void* l) {
    __builtin_amdgcn_global_load_lds(
        (const __attribute__((address_space(1))) void*)(uintptr_t)g,
        (__attribute__((address_space(3))) void*)(uint32_t)(uintptr_t)l,
        16, 0, 0);
}

// ---------------------------------------------------------------------------
// fused fp32->bf16 cast: 12 chunks of 1M elems (x = chunks 0..7, W's 8..11)
// NOTE: Wq/Wk/Wv land CONTIGUOUS in ws -> they form W_cat[3072][1024].
// ---------------------------------------------------------------------------
__global__ __launch_bounds__(256)
void cvt_all(const float* __restrict__ x,  const float* __restrict__ Wq,
             const float* __restrict__ Wk, const float* __restrict__ Wv,
             const float* __restrict__ Wo,
             bf16* __restrict__ xb, bf16* __restrict__ Wqb,
             bf16* __restrict__ Wkb, bf16* __restrict__ Wvb,
             bf16* __restrict__ Wob)
{
    const size_t CH = (size_t)1024*1024;
    int c = blockIdx.y;
    const float* src; bf16* dst;
    if (c < 8)       { src = x  + (size_t)c*CH; dst = xb  + (size_t)c*CH; }
    else if (c == 8) { src = Wq; dst = Wqb; }
    else if (c == 9) { src = Wk; dst = Wkb; }
    else if (c ==10) { src = Wv; dst = Wvb; }
    else             { src = Wo; dst = Wob; }
    int i = (blockIdx.x * 256 + threadIdx.x) * 8;
    float4 a = *(const float4*)(src + i);
    float4 b = *(const float4*)(src + i + 4);
    union { bf16 h[8]; uint4 v; } pk;
    pk.h[0] = __float2bfloat16(a.x); pk.h[1] = __float2bfloat16(a.y);
    pk.h[2] = __float2bfloat16(a.z); pk.h[3] = __float2bfloat16(a.w);
    pk.h[4] = __float2bfloat16(b.x); pk.h[5] = __float2bfloat16(b.y);
    pk.h[6] = __float2bfloat16(b.z); pk.h[7] = __float2bfloat16(b.w);
    *(uint4*)(dst + i) = pk.v;
}

// ---------------------------------------------------------------------------
// GEMM v3: 128x128 tile, BK=32, SINGLE-BARRIER PING-PONG (v11's flash win
// ported): stage tile k+1 into buf^1 right after the barrier, compute tile k
// — the barrier's vmcnt drain lands after 16 MFMAs of compute. XOR-swizzled
// LDS [128][32] (phys 16B-group = logical ^ (row&3); rows are 64B = 4 groups).
// MODE 0: bf16 *scale; 1: fp32; 2: bf16 transposed C^T[n][M_TOT].
// ---------------------------------------------------------------------------
template<int MODE>
__device__ __forceinline__
void gemm128_body(const bf16* __restrict__ A, const bf16* __restrict__ W,
                  const float* __restrict__ bias, void* __restrict__ Cout,
                  float scale, int m0, int n0w, int n0c,
                  bf16 (*As)[128*32], bf16 (*Bs)[128*32])
{
    constexpr int K = D_MODEL, N = D_MODEL;
    const int tid  = threadIdx.x;
    const int wv   = tid >> 6;
    const int lane = tid & 63;
    const int quad = lane >> 4;
    const int l16  = lane & 15;
    const int wr   = wv >> 1, wc = wv & 1;

    // staging: lane -> (row_off = lane>>2, fetch group = (lane&3)^(row_off&3))
    // => LDS_phys[r][g] = global[r][g ^ (r&3)]
    const int srow4 = lane >> 2;              // 0..15
    const int sg4   = (lane & 3) ^ (srow4 & 3);
    const bf16* Ag = A + (size_t)(m0  + srow4)*K + sg4*8;
    const bf16* Wg = W + (size_t)(n0w + srow4)*K + sg4*8;

    f32x4 acc[4][4];
    #pragma unroll
    for (int i = 0; i < 4; ++i)
        #pragma unroll
        for (int j = 0; j < 4; ++j) acc[i][j] = (f32x4){0.f,0.f,0.f,0.f};

    // prologue: stage k0=0 into buf 0 (wave wv covers rows [wv*32, +32))
    #pragma unroll
    for (int t = 0; t < 2; ++t) {
        int row0 = wv*32 + t*16;
        gld_lds16(Ag + (size_t)row0*K, As[0] + row0*32);
        gld_lds16(Wg + (size_t)row0*K, Bs[0] + row0*32);
    }

    const int fgo = (quad ^ (l16 & 3)) * 8;   // fragment phys-group offset

    for (int k0 = 0; k0 < K; k0 += 32) {
        const int cur = (k0 >> 5) & 1;
        __syncthreads();   // drains staging of cur; fences reads of cur^1
        if (k0 + 32 < K) {
            #pragma unroll
            for (int t = 0; t < 2; ++t) {
                int row0 = wv*32 + t*16;
                gld_lds16(Ag + (size_t)row0*K + (k0+32), As[cur^1] + row0*32);
                gld_lds16(Wg + (size_t)row0*K + (k0+32), Bs[cur^1] + row0*32);
            }
        }
        bf16x8 af[4], bfb[4];
        #pragma unroll
        for (int i = 0; i < 4; ++i)
            af[i] = *(const bf16x8*)(As[cur] + (wr*64 + i*16 + l16)*32 + fgo);
        #pragma unroll
        for (int j = 0; j < 4; ++j)
            bfb[j] = *(const bf16x8*)(Bs[cur] + (wc*64 + j*16 + l16)*32 + fgo);
        #pragma unroll
        for (int i = 0; i < 4; ++i)
            #pragma unroll
            for (int j = 0; j < 4; ++j)
                acc[i][j] = __builtin_amdgcn_mfma_f32_16x16x32_bf16(af[i], bfb[j], acc[i][j], 0,0,0);
    }

    #pragma unroll
    for (int j = 0; j < 4; ++j) {
        int n = n0c + wc*64 + j*16 + l16;
        float bv = bias[n];
        #pragma unroll
        for (int i = 0; i < 4; ++i) {
            if constexpr (MODE == 2) {
                union { bf16 hh[4]; uint2 u; } pk;
                #pragma unroll
                for (int r = 0; r < 4; ++r)
                    pk.hh[r] = __float2bfloat16((acc[i][j][r] + bv) * scale);
                int mb = m0 + wr*64 + i*16 + quad*4;
                *(uint2*)((bf16*)Cout + (size_t)n*M_TOT + mb) = pk.u;
            } else {
                #pragma unroll
                for (int r = 0; r < 4; ++r) {
                    int m = m0 + wr*64 + i*16 + quad*4 + r;
                    float v = (acc[i][j][r] + bv) * scale;
                    if constexpr (MODE == 0)
                        ((bf16*)Cout)[(size_t)m*N + n] = __float2bfloat16(v);
                    else
                        ((float*)Cout)[(size_t)m*N + n] = v;
                }
            }
        }
    }
}

#define QSCALE (0.125f * 1.44269504089f)   // fold log2(e): exp(s)=exp2(s*log2e)

// single fused QKV GEMM over W_cat[3072][1024]; n-tile selects output mode
__global__ __launch_bounds__(256)
void gemm_qkv(const bf16* __restrict__ xb, const bf16* __restrict__ Wcat,
              const float* __restrict__ bq, const float* __restrict__ bk,
              const float* __restrict__ bv,
              bf16* __restrict__ Qp, bf16* __restrict__ Kp, bf16* __restrict__ VT)
{
    __shared__ __attribute__((aligned(16))) bf16 As[2][128*32];
    __shared__ __attribute__((aligned(16))) bf16 Bs[2][128*32];
    const int m0 = blockIdx.x * 128, n0w = blockIdx.y * 128;
    const int sel = n0w >> 10, n0c = n0w & 1023;
    if (sel == 0)
        gemm128_body<0>(xb, Wcat, bq, Qp, QSCALE, m0, n0w, n0c, As, Bs);
    else if (sel == 1)
        gemm128_body<0>(xb, Wcat, bk, Kp, 1.0f, m0, n0w, n0c, As, Bs);
    else
        gemm128_body<2>(xb, Wcat, bv, VT, 1.0f, m0, n0w, n0c, As, Bs);
}

__global__ __launch_bounds__(256)
void gemm_out(const bf16* __restrict__ Cp, const bf16* __restrict__ Wo,
              const float* __restrict__ bo, float* __restrict__ out)
{
    __shared__ __attribute__((aligned(16))) bf16 As[2][128*32];
    __shared__ __attribute__((aligned(16))) bf16 Bs[2][128*32];
    const int n0 = blockIdx.y * 128;
    gemm128_body<1>(Cp, Wo, bo, out, 1.0f, blockIdx.x*128, n0, n0, As, Bs);
}

// ---------------------------------------------------------------------------
// Flash attention v12 = v11 + l-via-MFMA: row sums l = P·ones ride the matrix
// pipe (one extra 16x16x16 MFMA per (ktile,g) with constant ones B-frag)
// instead of 32 VALU adds/iter; result lands in o's exact C-layout
// (row=quad*4+r) so the epilogue shuffle-reduce disappears too.
// ---------------------------------------------------------------------------
__global__ __launch_bounds__(256)
void flash_attn12(const bf16* __restrict__ Q, const bf16* __restrict__ Kp,
                  const bf16* __restrict__ VT, bf16* __restrict__ ctx)
{
    __shared__ __attribute__((aligned(16))) bf16 Ks[2][64*64]; // swizzled [key][d]
    __shared__ __attribute__((aligned(16))) bf16 Vs[2][64*64]; // swizzled [d][key]

    const int tid  = threadIdx.x;
    const int wv   = tid >> 6;
    const int lane = tid & 63;
    const int quad = lane >> 4;
    const int l16  = lane & 15;
    const int l8   = l16 & 7;

    const int b  = blockIdx.z;
    const int h  = blockIdx.y;
    const int q0 = blockIdx.x * 128;

    const bf16* kbase = Kp + (size_t)(b*SEQ)*D_MODEL + h*64;
    const bf16* vbase = VT + (size_t)(h*64)*M_TOT + (size_t)b*SEQ;

    const int srow_off = lane >> 3;
    const int sgc      = (lane & 7) ^ srow_off;

    // Q fragments for both 16q groups (rows wv*32 + g*16 + l16)
    bf16x8 aq[2][2];
    #pragma unroll
    for (int g = 0; g < 2; ++g) {
        const bf16* qp = Q + (size_t)(b*SEQ + q0 + wv*32 + g*16 + l16)*D_MODEL + h*64;
        aq[g][0] = *(const bf16x8*)(qp + quad*8);
        aq[g][1] = *(const bf16x8*)(qp + 32 + quad*8);
    }

    const bf16x4 vones = {(short)0x3F80, (short)0x3F80, (short)0x3F80, (short)0x3F80};

    f32x4 l_acc[2];
    f32x4 o[2][4];
    #pragma unroll
    for (int g = 0; g < 2; ++g) {
        l_acc[g] = (f32x4){0.f,0.f,0.f,0.f};
        #pragma unroll
        for (int j = 0; j < 4; ++j) o[g][j] = (f32x4){0.f,0.f,0.f,0.f};
    }

    // prologue: stage tile 0 into buf 0
    #pragma unroll
    for (int t = 0; t < 2; ++t) {
        int row0 = wv*16 + t*8;
        gld_lds16(kbase + (size_t)(row0 + srow_off)*D_MODEL + sgc*8,
                  &Ks[0][row0*64]);
        gld_lds16(vbase + (size_t)(row0 + srow_off)*M_TOT + sgc*8,
                  &Vs[0][row0*64]);
    }

    for (int kt = 0; kt < SEQ/64; ++kt) {
        const int cur = kt & 1;
        __syncthreads();   // drains staging of cur; fences prev reads of cur^1
        if (kt + 1 < SEQ/64) {
            #pragma unroll
            for (int t = 0; t < 2; ++t) {
                int row0 = wv*16 + t*8;
                gld_lds16(kbase + (size_t)((kt+1)*64 + row0 + srow_off)*D_MODEL + sgc*8,
                          &Ks[cur^1][row0*64]);
                gld_lds16(vbase + (size_t)(row0 + srow_off)*M_TOT + (kt+1)*64 + sgc*8,
                          &Vs[cur^1][row0*64]);
            }
        }

        // S^T = K·Q^T per ktile; exp2; pack P into 16x16x16 A-frags (regs)
        bf16x4 paf[2][4];
        #pragma unroll
        for (int ktile = 0; ktile < 4; ++ktile) {
            bf16x8 ak[2];
            #pragma unroll
            for (int ks = 0; ks < 2; ++ks)
                ak[ks] = *(const bf16x8*)(&Ks[cur][(ktile*16 + l16)*64
                                          + ((ks*4 + quad) ^ l8)*8]);
            #pragma unroll
            for (int g = 0; g < 2; ++g) {
                f32x4 st = (f32x4){0.f,0.f,0.f,0.f};
                st = __builtin_amdgcn_mfma_f32_16x16x32_bf16(ak[0], aq[g][0], st, 0,0,0);
                st = __builtin_amdgcn_mfma_f32_16x16x32_bf16(ak[1], aq[g][1], st, 0,0,0);
                union { bf16 hh[4]; bf16x4 v; } pk;
                #pragma unroll
                for (int r = 0; r < 4; ++r)
                    pk.hh[r] = __float2bfloat16(__builtin_amdgcn_exp2f(st[r]));
                paf[g][ktile] = pk.v;
                // l += P·1 on the matrix pipe (C-layout matches o)
                l_acc[g] = __builtin_amdgcn_mfma_f32_16x16x16bf16_1k(
                               paf[g][ktile], vones, l_acc[g], 0, 0, 0);
            }
        }

        // O += P @ V via 16x16x16 MFMA (A from regs; B = b64 reads from Vs)
        #pragma unroll
        for (int ktile = 0; ktile < 4; ++ktile)
            #pragma unroll
            for (int jt = 0; jt < 4; ++jt) {
                bf16x4 bv = *(const bf16x4*)(&Vs[cur][(jt*16 + l16)*64
                              + ((ktile*2 + (quad>>1)) ^ l8)*8 + (quad&1)*4]);
                #pragma unroll
                for (int g = 0; g < 2; ++g)
                    o[g][jt] = __builtin_amdgcn_mfma_f32_16x16x16bf16_1k(
                                   paf[g][ktile], bv, o[g][jt], 0, 0, 0);
            }
    }

    // epilogue: l_acc[g][r] is the full row sum for q-local = quad*4+r —
    // same layout as o; no cross-lane reduction needed.
    #pragma unroll
    for (int g = 0; g < 2; ++g)
        #pragma unroll
        for (int r = 0; r < 4; ++r) {
            float inv = 1.f / l_acc[g][r];
            int q = q0 + wv*32 + g*16 + quad*4 + r;
            #pragma unroll
            for (int j = 0; j < 4; ++j)
                ctx[(size_t)(b*SEQ + q)*D_MODEL + h*64 + j*16 + l16] =
                    __float2bfloat16(o[g][j][r] * inv);
        }
}

extern "C" void kernel_launch(void* const* d_in, const int* in_sizes, int n_in,
                              void* d_out, int out_size, void* d_ws, size_t ws_size,
                              hipStream_t stream)
{
    const float* x  = (const float*)d_in[0];
    const float* Wq = (const float*)d_in[1];
    const float* bq = (const float*)d_in[2];
    const float* Wk = (const float*)d_in[3];
    const float* bk = (const float*)d_in[4];
    const float* Wv = (const float*)d_in[5];
    const float* bv = (const float*)d_in[6];
    const float* Wo = (const float*)d_in[7];
    const float* bo = (const float*)d_in[8];

    const size_t NEL = (size_t)M_TOT * D_MODEL;
    const size_t WEL = (size_t)D_MODEL * D_MODEL;

    bf16* ws  = (bf16*)d_ws;
    bf16* xb  = ws;
    bf16* Wqb = ws + NEL;          // Wqb/Wkb/Wvb contiguous = W_cat[3072][1024]
    bf16* Wkb = Wqb + WEL;
    bf16* Wvb = Wkb + WEL;
    bf16* Wob = Wvb + WEL;
    bf16* Qp  = Wob + WEL;
    bf16* Kp  = Qp + NEL;
    bf16* VT  = Kp + NEL;
    bf16* Cp  = VT + NEL;
    float* out = (float*)d_out;

    dim3 blk(256);
    hipLaunchKernelGGL(cvt_all, dim3(512, 12), blk, 0, stream,
                       x, Wq, Wk, Wv, Wo, xb, Wqb, Wkb, Wvb, Wob);
    hipLaunchKernelGGL(gemm_qkv, dim3(M_TOT/128, 3*D_MODEL/128), blk, 0, stream,
                       xb, Wqb, bq, bk, bv, Qp, Kp, VT);
    hipLaunchKernelGGL(flash_attn12, dim3(SEQ/128, N_HEADS, BATCH), blk, 0, stream,
                       Qp, Kp, VT, Cp);
    hipLaunchKernelGGL(gemm_out, dim3(M_TOT/128, D_MODEL/128), blk, 0, stream,
                       Cp, Wob, bo, out);
}